// Round 13
// baseline (95.126 us; speedup 1.0000x reference)
//
#include <hip/hip_runtime.h>

// LayerStacks round 13: two waves per 16-sample MFMA tile => 2x wave count.
// 1024-thread block covers 512 samples; wave pair (2t, 2t+1) owns tile t:
//   stage1: h=0 wave does x_base stream (W1b + Wout[64:192) dot),
//           h=1 wave does x_pa  stream (W1pa + Wout[192:320) dot).
//   stage2: h gets L2 neurons 32h..32h+31 (2 of 4 N-tiles) + partial Wout dot.
//   finalize: h=0 wave, lanes 0-15 sum {accA, accP, pA, pB} from scratch.
// Total waves = 2*B/64/... = 8192 = 32/CU (hardware max) vs 16/CU in R9-R12,
// which were grid-pinned. Latency-bound kernel (all pipes <40%) => TLP lever.
// Compute math identical to R8-R10 (verified).

#define NB 6
#define BT 1024                 // threads per block
#define SPB 512                 // samples per block
#define MAXT (SPB / 16 + NB)    // max tiles = 38

typedef _Float16 h2 __attribute__((ext_vector_type(2)));
typedef _Float16 h8 __attribute__((ext_vector_type(8)));
typedef float f4 __attribute__((ext_vector_type(4)));

__device__ __forceinline__ h2 pk2(float x, float y) {
    return __builtin_bit_cast(h2, __builtin_amdgcn_cvt_pkrtz(x, y));
}

__device__ __forceinline__ h8 pack8(const float4 a, const float4 b) {
    h2 p0 = pk2(a.x, a.y), p1 = pk2(a.z, a.w);
    h2 p2 = pk2(b.x, b.y), p3 = pk2(b.z, b.w);
    h8 r;
    r[0] = p0[0]; r[1] = p0[1]; r[2] = p1[0]; r[3] = p1[1];
    r[4] = p2[0]; r[5] = p2[1]; r[6] = p3[0]; r[7] = p3[1];
    return r;
}

__device__ __forceinline__ float actv(float v) {
    float u = fminf(fmaxf(v, 0.0f), 1.0f);
    return u * u * (255.0f / 256.0f);
}

__global__ __launch_bounds__(BT, 8)
void layerstacks_mfma(const float* __restrict__ x_base,
                      const float* __restrict__ x_pa,
                      const float* __restrict__ mobility,
                      const int*   __restrict__ ply,
                      const float* __restrict__ W1b,
                      const float* __restrict__ b1b,
                      const float* __restrict__ W1pa,
                      const float* __restrict__ b1pa,
                      const float* __restrict__ W2,
                      const float* __restrict__ b2,
                      const float* __restrict__ Wout,
                      const float* __restrict__ bout,
                      float* __restrict__ out)
{
    __shared__ __align__(16) _Float16 sW1[NB][2][4][4][9][8];   // 27.6 KB
    __shared__ __align__(16) _Float16 sW2[NB][4][4][16][8];     // 24.6 KB
    __shared__ float sWo0[NB][64];
    __shared__ float sB2[NB][64];
    __shared__ float sB1[NB][4][8];
    __shared__ float sBout[NB];
    __shared__ int   sList[SPB + NB * 16];
    __shared__ __align__(16) char sL1[8 * 1280];   // 8 concurrent tiles x 16 rows x 80B
    __shared__ int sCnt[8], sCur[8], sTb[MAXT + 2];
    __shared__ int sNt;

    const int tid   = threadIdx.x;
    const int lane  = tid & 63;
    const int w     = tid >> 6;          // 0..15
    const int slot  = w >> 1;            // tile slot 0..7
    const int h     = w & 1;             // stream half
    const int gbase = blockIdx.x * SPB;

    // ---------------- phase 0: staging --------------------------------------
    if (tid < 8) { sCnt[tid] = 0; }

    for (int e = tid; e < NB * 2 * 4 * 4 * 9 * 8; e += BT) {
        int i = e & 7;
        int rest = e >> 3;
        int n = rest % 9;   rest /= 9;
        int kb = rest & 3;  rest >>= 2;
        int t = rest & 3;   rest >>= 2;
        int st = rest & 1;
        int b = rest >> 1;
        int k = t * 32 + kb * 8 + i;
        float v;
        if (n < 8) {
            const float* Wx = st ? W1pa : W1b;
            v = Wx[b * 1032 + n * 129 + k];
        } else {
            v = st ? Wout[b * 320 + 192 + k] : Wout[b * 320 + 64 + k];
        }
        sW1[b][st][t][kb][n][i] = (_Float16)v;
    }
    for (int e = tid; e < NB * 4 * 4 * 16 * 8; e += BT) {
        int i = e & 7;
        int j = (e >> 3) & 15;
        int kb = (e >> 7) & 3;
        int T = (e >> 9) & 3;
        int b = e >> 11;
        int n = T * 16 + j;
        int k = kb * 8 + i;
        int u = k >> 1;
        int colw = (k & 1) ? (16 + u) : u;
        sW2[b][T][kb][j][i] = (_Float16)W2[b * 2048 + n * 32 + colw];
    }
    for (int e = tid; e < NB * 64; e += BT) {
        int b = e >> 6, n = e & 63;
        sWo0[b][n] = Wout[b * 320 + n];
        sB2[b][n]  = b2[e];
    }
    if (tid < NB * 4 * 8) {
        int n = tid & 7, which = (tid >> 3) & 3, b = tid >> 5;
        float v;
        if (which == 0)      v = b1b[b * 8 + n];
        else if (which == 1) v = b1pa[b * 8 + n];
        else if (which == 2) v = W1b [b * 1032 + n * 129 + 128];
        else                 v = W1pa[b * 1032 + n * 129 + 128];
        sB1[b][which][n] = v;
    }
    if (tid < NB) sBout[tid] = bout[tid];
    for (int e = tid; e < SPB + NB * 16; e += BT) sList[e] = -1;

    const int bb = (tid < SPB) ? (ply[gbase + tid] / 10) : -1;
    __syncthreads();

    // ---------------- phase 1: ballot-aggregated counts ---------------------
    #pragma unroll
    for (int b = 0; b < NB; ++b) {
        unsigned long long mk = __ballot(bb == b);
        if (bb == b) {
            int lead = __ffsll((long long)mk) - 1;
            if (lane == lead) atomicAdd(&sCnt[b], __popcll(mk));
        }
    }
    __syncthreads();

    // ---------------- phase 2: offsets + tile->bucket map -------------------
    if (tid == 0) {
        int off = 0, tt = 0;
        for (int b = 0; b < NB; ++b) {
            sCur[b] = off;
            int ntl = (sCnt[b] + 15) >> 4;
            for (int q = 0; q < ntl; ++q) sTb[tt++] = b;
            off += ntl << 4;
        }
        sNt = tt;
    }
    __syncthreads();

    // ---------------- phase 3: scatter local indices ------------------------
    #pragma unroll
    for (int b = 0; b < NB; ++b) {
        unsigned long long mk = __ballot(bb == b);
        if (bb == b) {
            int lead = __ffsll((long long)mk) - 1;
            int pfx = __popcll(mk & ((1ull << lane) - 1ull));
            int base = 0;
            if (lane == lead) base = atomicAdd(&sCur[b], __popcll(mk));
            base = __shfl(base, lead);
            sList[base + pfx] = tid;
        }
    }
    __syncthreads();

    // ---------------- main: rounds of 8 tiles, 2 waves per tile -------------
    const int ntiles = sNt;
    const int nrounds = (ntiles + 7) >> 3;
    const int col = lane & 15;
    const int qd  = lane >> 4;
    char* lb = sL1 + slot * 1280;

    for (int rnd = 0; rnd < nrounds; ++rnd) {
        const int tl = rnd * 8 + slot;
        const bool active = (tl < ntiles);
        int bkt = 0, t16 = 0;

        // ==================== stage 1 (split by stream h) ===================
        if (active) {
            bkt = sTb[tl];
            t16 = tl << 4;

            const int sl0 = sList[t16 + qd * 4 + 0];
            const int sl1 = sList[t16 + qd * 4 + 1];
            const int sl2 = sList[t16 + qd * 4 + 2];
            const int sl3 = sList[t16 + qd * 4 + 3];
            int sA = sList[t16 + col];
            if (sA < 0) sA = sList[t16];

            const float* xr = (h ? x_pa : x_base) + (size_t)(gbase + sA) * 128 + qd * 8;
            const float4 x00 = *(const float4*)(xr + 0);
            const float4 x01 = *(const float4*)(xr + 4);
            const float4 x10 = *(const float4*)(xr + 32);
            const float4 x11 = *(const float4*)(xr + 36);
            const float4 x20 = *(const float4*)(xr + 64);
            const float4 x21 = *(const float4*)(xr + 68);
            const float4 x30 = *(const float4*)(xr + 96);
            const float4 x31 = *(const float4*)(xr + 100);

            const int c7 = col & 7;
            const bool a8 = (col < 8);
            const int ncl = a8 ? col : 8;

            const h8 w0 = *(const h8*)&sW1[bkt][h][0][qd][ncl][0];
            const h8 w1 = *(const h8*)&sW1[bkt][h][1][qd][ncl][0];
            const h8 w2f = *(const h8*)&sW1[bkt][h][2][qd][ncl][0];
            const h8 w3 = *(const h8*)&sW1[bkt][h][3][qd][ncl][0];

            const float mob0 = (sl0 >= 0) ? fminf(mobility[gbase + sl0] * (7.0f / 255.0f), 1.0f) : 0.0f;
            const float mob1 = (sl1 >= 0) ? fminf(mobility[gbase + sl1] * (7.0f / 255.0f), 1.0f) : 0.0f;
            const float mob2 = (sl2 >= 0) ? fminf(mobility[gbase + sl2] * (7.0f / 255.0f), 1.0f) : 0.0f;
            const float mob3 = (sl3 >= 0) ? fminf(mobility[gbase + sl3] * (7.0f / 255.0f), 1.0f) : 0.0f;
            const float b1v = sB1[bkt][h][c7];        // b1b or b1pa
            const float mwv = sB1[bkt][2 + h][c7];    // mobility col

            f4 c;
            c[0] = a8 ? b1v + mwv * mob0 : 0.0f;
            c[1] = a8 ? b1v + mwv * mob1 : 0.0f;
            c[2] = a8 ? b1v + mwv * mob2 : 0.0f;
            c[3] = a8 ? b1v + mwv * mob3 : 0.0f;

            c = __builtin_amdgcn_mfma_f32_16x16x32_f16(pack8(x00, x01), w0, c, 0, 0, 0);
            c = __builtin_amdgcn_mfma_f32_16x16x32_f16(pack8(x10, x11), w1, c, 0, 0, 0);
            c = __builtin_amdgcn_mfma_f32_16x16x32_f16(pack8(x20, x21), w2f, c, 0, 0, 0);
            c = __builtin_amdgcn_mfma_f32_16x16x32_f16(pack8(x30, x31), w3, c, 0, 0, 0);

            if (col < 8) {
                #pragma unroll
                for (int r = 0; r < 4; ++r) {
                    const int row = qd * 4 + r;
                    const float v = c[r];
                    *(h2*)(lb + row * 80 + h * 32 + col * 4) =
                        pk2(fminf(v * v * (255.0f / 256.0f), 1.0f),
                            fminf(fmaxf(v, 0.0f), 1.0f));
                }
            } else if (col == 8) {
                #pragma unroll
                for (int r = 0; r < 4; ++r)
                    *(float*)(lb + (qd * 4 + r) * 80 + 64 + h * 4) = c[r];
            }
        }
        __syncthreads();

        // ==================== stage 2 (split by N-tile pair) ================
        if (active) {
            const h8 a2 = *(const h8*)(lb + col * 80 + qd * 16);
            const int T0 = 2 * h, T1 = 2 * h + 1;
            const float s0 = sB2[bkt][T0 * 16 + col];
            const float s1 = sB2[bkt][T1 * 16 + col];
            f4 c20 = {s0, s0, s0, s0};
            f4 c21 = {s1, s1, s1, s1};
            c20 = __builtin_amdgcn_mfma_f32_16x16x32_f16(a2, *(const h8*)&sW2[bkt][T0][qd][col][0], c20, 0, 0, 0);
            c21 = __builtin_amdgcn_mfma_f32_16x16x32_f16(a2, *(const h8*)&sW2[bkt][T1][qd][col][0], c21, 0, 0, 0);

            const float wo0 = sWo0[bkt][T0 * 16 + col];
            const float wo1 = sWo0[bkt][T1 * 16 + col];
            float p0 = actv(c20[0]) * wo0 + actv(c21[0]) * wo1;
            float p1 = actv(c20[1]) * wo0 + actv(c21[1]) * wo1;
            float p2 = actv(c20[2]) * wo0 + actv(c21[2]) * wo1;
            float p3 = actv(c20[3]) * wo0 + actv(c21[3]) * wo1;
            #pragma unroll
            for (int m = 1; m < 16; m <<= 1) {
                p0 += __shfl_xor(p0, m, 64);
                p1 += __shfl_xor(p1, m, 64);
                p2 += __shfl_xor(p2, m, 64);
                p3 += __shfl_xor(p3, m, 64);
            }
            if (col == 0) {
                *(float*)(lb + (qd * 4 + 0) * 80 + 72 + h * 4) = p0;
                *(float*)(lb + (qd * 4 + 1) * 80 + 72 + h * 4) = p1;
                *(float*)(lb + (qd * 4 + 2) * 80 + 72 + h * 4) = p2;
                *(float*)(lb + (qd * 4 + 3) * 80 + 72 + h * 4) = p3;
            }
        }
        __syncthreads();

        // ==================== finalize (h=0 wave, 16 lanes) =================
        if (active && h == 0 && lane < 16) {
            const int row = lane;
            const int sl = sList[t16 + row];
            if (sl >= 0) {
                const char* rp = lb + row * 80;
                out[gbase + sl] = sBout[bkt]
                                + *(const float*)(rp + 64) + *(const float*)(rp + 68)
                                + *(const float*)(rp + 72) + *(const float*)(rp + 76);
            }
        }
        __syncthreads();
    }
}

extern "C" void kernel_launch(void* const* d_in, const int* in_sizes, int n_in,
                              void* d_out, int out_size, void* d_ws, size_t ws_size,
                              hipStream_t stream) {
    const float* x_base   = (const float*)d_in[0];
    const float* x_pa     = (const float*)d_in[1];
    const float* mobility = (const float*)d_in[2];
    const int*   ply      = (const int*)d_in[3];
    const float* W1b      = (const float*)d_in[4];
    const float* b1b      = (const float*)d_in[5];
    const float* W1pa     = (const float*)d_in[6];
    const float* b1pa     = (const float*)d_in[7];
    const float* W2       = (const float*)d_in[8];
    const float* b2       = (const float*)d_in[9];
    const float* Wout     = (const float*)d_in[10];
    const float* bout     = (const float*)d_in[11];
    float* out = (float*)d_out;

    const int B = in_sizes[3];              // 262144 (multiple of 512)
    const int blocks = B / SPB;             // 512 blocks x 1024 threads
    layerstacks_mfma<<<blocks, BT, 0, stream>>>(
        x_base, x_pa, mobility, ply, W1b, b1b, W1pa, b1pa, W2, b2, Wout, bout, out);
}

// Round 14
// 70.178 us; speedup vs baseline: 1.3555x; 1.3555x over previous
//
#include <hip/hip_runtime.h>

// LayerStacks round 14: R10 (best, 60.8us) + forced load flight depth.
// Diagnosis across R8-R13: VGPR pinned at 64 => at most ~2-4 of the 16 x-loads
// in flight => ~8 exposed latency windows per tile. R13 proved occupancy is
// NOT the lever (86% occ, slower). Fix the register ceiling + pin the loads:
//   1) __launch_bounds__(512, 2): allocator may use up to 256 VGPR.
//   2) asm volatile "memory" fence after the load cluster: no IR/MIR pass may
//      sink a load below it => all 16 global + 8 LDS weight loads issue first.
// Everything else identical to R10.

#define NB 6
#define BT 512
#define NW (BT / 64)

typedef _Float16 h2 __attribute__((ext_vector_type(2)));
typedef _Float16 h8 __attribute__((ext_vector_type(8)));
typedef float f4 __attribute__((ext_vector_type(4)));

__device__ __forceinline__ h2 pk2(float x, float y) {
    return __builtin_bit_cast(h2, __builtin_amdgcn_cvt_pkrtz(x, y));
}

__device__ __forceinline__ h8 pack8(const float4 a, const float4 b) {
    h2 p0 = pk2(a.x, a.y), p1 = pk2(a.z, a.w);
    h2 p2 = pk2(b.x, b.y), p3 = pk2(b.z, b.w);
    h8 r;
    r[0] = p0[0]; r[1] = p0[1]; r[2] = p1[0]; r[3] = p1[1];
    r[4] = p2[0]; r[5] = p2[1]; r[6] = p3[0]; r[7] = p3[1];
    return r;
}

__device__ __forceinline__ float actv(float v) {
    float u = fminf(fmaxf(v, 0.0f), 1.0f);
    return u * u * (255.0f / 256.0f);
}

__global__ __launch_bounds__(BT, 2)
void layerstacks_mfma(const float* __restrict__ x_base,
                      const float* __restrict__ x_pa,
                      const float* __restrict__ mobility,
                      const int*   __restrict__ ply,
                      const float* __restrict__ W1b,
                      const float* __restrict__ b1b,
                      const float* __restrict__ W1pa,
                      const float* __restrict__ b1pa,
                      const float* __restrict__ W2,
                      const float* __restrict__ b2,
                      const float* __restrict__ Wout,
                      const float* __restrict__ bout,
                      float* __restrict__ out)
{
    __shared__ __align__(16) _Float16 sW1[NB][2][4][4][9][8];   // 27.6 KB
    __shared__ __align__(16) _Float16 sW2[NB][4][4][16][8];     // 24.6 KB
    __shared__ float sWo0[NB][64];
    __shared__ float sB2[NB][64];
    __shared__ float sB1[NB][4][8];
    __shared__ float sBout[NB];
    __shared__ float sMob[BT];
    __shared__ int   sList[BT + NB * 16];
    __shared__ __align__(16) char sL1[NW * 1280];
    __shared__ int sCnt[8], sCur[8], sTb[40];
    __shared__ int sNt;

    const int tid   = threadIdx.x;
    const int lane  = tid & 63;
    const int w     = tid >> 6;
    const int gbase = blockIdx.x * BT;

    // ---------------- phase 0: staging --------------------------------------
    if (tid < 8) { sCnt[tid] = 0; }

    for (int e = tid; e < NB * 2 * 4 * 4 * 9 * 8; e += BT) {
        int i = e & 7;
        int rest = e >> 3;
        int n = rest % 9;   rest /= 9;
        int kb = rest & 3;  rest >>= 2;
        int t = rest & 3;   rest >>= 2;
        int st = rest & 1;
        int b = rest >> 1;
        int k = t * 32 + kb * 8 + i;
        float v;
        if (n < 8) {
            const float* Wx = st ? W1pa : W1b;
            v = Wx[b * 1032 + n * 129 + k];
        } else {
            v = st ? Wout[b * 320 + 192 + k] : Wout[b * 320 + 64 + k];
        }
        sW1[b][st][t][kb][n][i] = (_Float16)v;
    }
    for (int e = tid; e < NB * 4 * 4 * 16 * 8; e += BT) {
        int i = e & 7;
        int j = (e >> 3) & 15;
        int kb = (e >> 7) & 3;
        int T = (e >> 9) & 3;
        int b = e >> 11;
        int n = T * 16 + j;
        int k = kb * 8 + i;
        int u = k >> 1;
        int colw = (k & 1) ? (16 + u) : u;
        sW2[b][T][kb][j][i] = (_Float16)W2[b * 2048 + n * 32 + colw];
    }
    for (int e = tid; e < NB * 64; e += BT) {
        int b = e >> 6, n = e & 63;
        sWo0[b][n] = Wout[b * 320 + n];
        sB2[b][n]  = b2[e];
    }
    if (tid < NB * 4 * 8) {
        int n = tid & 7, which = (tid >> 3) & 3, b = tid >> 5;
        float v;
        if (which == 0)      v = b1b[b * 8 + n];
        else if (which == 1) v = b1pa[b * 8 + n];
        else if (which == 2) v = W1b [b * 1032 + n * 129 + 128];
        else                 v = W1pa[b * 1032 + n * 129 + 128];
        sB1[b][which][n] = v;
    }
    if (tid < NB) sBout[tid] = bout[tid];
    sMob[tid] = fminf(mobility[gbase + tid] * (7.0f / 255.0f), 1.0f);
    for (int e = tid; e < BT + NB * 16; e += BT) sList[e] = -1;

    const int bb = ply[gbase + tid] / 10;
    __syncthreads();

    // ---------------- phase 1: ballot-aggregated counts ---------------------
    #pragma unroll
    for (int b = 0; b < NB; ++b) {
        unsigned long long mk = __ballot(bb == b);
        if (bb == b) {
            int lead = __ffsll((long long)mk) - 1;
            if (lane == lead) atomicAdd(&sCnt[b], __popcll(mk));
        }
    }
    __syncthreads();

    // ---------------- phase 2: offsets + tile->bucket map -------------------
    if (tid == 0) {
        int off = 0, tt = 0;
        for (int b = 0; b < NB; ++b) {
            sCur[b] = off;
            int ntl = (sCnt[b] + 15) >> 4;
            for (int q = 0; q < ntl; ++q) sTb[tt++] = b;
            off += ntl << 4;
        }
        sNt = tt;
    }
    __syncthreads();

    // ---------------- phase 3: scatter local indices ------------------------
    #pragma unroll
    for (int b = 0; b < NB; ++b) {
        unsigned long long mk = __ballot(bb == b);
        if (bb == b) {
            int lead = __ffsll((long long)mk) - 1;
            int pfx = __popcll(mk & ((1ull << lane) - 1ull));
            int base = 0;
            if (lane == lead) base = atomicAdd(&sCur[b], __popcll(mk));
            base = __shfl(base, lead);
            sList[base + pfx] = tid;
        }
    }
    __syncthreads();

    // ---------------- main: per-wave MFMA tiles -----------------------------
    const int ntiles = sNt;
    const int col = lane & 15;
    const int qd  = lane >> 4;
    char* lb = sL1 + w * 1280;

    for (int tl = w; tl < ntiles; tl += NW) {
        const int bkt = sTb[tl];
        const int t16 = tl << 4;

        const int sl0 = sList[t16 + qd * 4 + 0];
        const int sl1 = sList[t16 + qd * 4 + 1];
        const int sl2 = sList[t16 + qd * 4 + 2];
        const int sl3 = sList[t16 + qd * 4 + 3];
        int sA = sList[t16 + col];
        if (sA < 0) sA = sList[t16];

        // ==== LOAD CLUSTER ==================================================
        const float* xbrow = x_base + (size_t)(gbase + sA) * 128 + qd * 8;
        const float* xprow = x_pa   + (size_t)(gbase + sA) * 128 + qd * 8;
        const float4 b00 = *(const float4*)(xbrow + 0);
        const float4 b01 = *(const float4*)(xbrow + 4);
        const float4 b10 = *(const float4*)(xbrow + 32);
        const float4 b11 = *(const float4*)(xbrow + 36);
        const float4 b20 = *(const float4*)(xbrow + 64);
        const float4 b21 = *(const float4*)(xbrow + 68);
        const float4 b30 = *(const float4*)(xbrow + 96);
        const float4 b31 = *(const float4*)(xbrow + 100);
        const float4 q00 = *(const float4*)(xprow + 0);
        const float4 q01 = *(const float4*)(xprow + 4);
        const float4 q10 = *(const float4*)(xprow + 32);
        const float4 q11 = *(const float4*)(xprow + 36);
        const float4 q20 = *(const float4*)(xprow + 64);
        const float4 q21 = *(const float4*)(xprow + 68);
        const float4 q30 = *(const float4*)(xprow + 96);
        const float4 q31 = *(const float4*)(xprow + 100);

        const int c7 = col & 7;
        const bool a8 = (col < 8);
        const int ncl = a8 ? col : 8;

        const h8 wa0 = *(const h8*)&sW1[bkt][0][0][qd][ncl][0];
        const h8 wa1 = *(const h8*)&sW1[bkt][0][1][qd][ncl][0];
        const h8 wa2 = *(const h8*)&sW1[bkt][0][2][qd][ncl][0];
        const h8 wa3 = *(const h8*)&sW1[bkt][0][3][qd][ncl][0];
        const h8 wp0 = *(const h8*)&sW1[bkt][1][0][qd][ncl][0];
        const h8 wp1 = *(const h8*)&sW1[bkt][1][1][qd][ncl][0];
        const h8 wp2 = *(const h8*)&sW1[bkt][1][2][qd][ncl][0];
        const h8 wp3 = *(const h8*)&sW1[bkt][1][3][qd][ncl][0];

        const float mob0 = (sl0 >= 0) ? sMob[sl0] : 0.0f;
        const float mob1 = (sl1 >= 0) ? sMob[sl1] : 0.0f;
        const float mob2 = (sl2 >= 0) ? sMob[sl2] : 0.0f;
        const float mob3 = (sl3 >= 0) ? sMob[sl3] : 0.0f;
        const float bb1 = sB1[bkt][0][c7], bp1 = sB1[bkt][1][c7];
        const float mwb = sB1[bkt][2][c7], mwp = sB1[bkt][3][c7];

        // Compiler fence: no pass may sink the loads above across this point.
        asm volatile("" ::: "memory");
        // ====================================================================

        f4 cb, cp;
        cb[0] = a8 ? bb1 + mwb * mob0 : 0.0f;
        cb[1] = a8 ? bb1 + mwb * mob1 : 0.0f;
        cb[2] = a8 ? bb1 + mwb * mob2 : 0.0f;
        cb[3] = a8 ? bb1 + mwb * mob3 : 0.0f;
        cp[0] = a8 ? bp1 + mwp * mob0 : 0.0f;
        cp[1] = a8 ? bp1 + mwp * mob1 : 0.0f;
        cp[2] = a8 ? bp1 + mwp * mob2 : 0.0f;
        cp[3] = a8 ? bp1 + mwp * mob3 : 0.0f;

        cb = __builtin_amdgcn_mfma_f32_16x16x32_f16(pack8(b00, b01), wa0, cb, 0, 0, 0);
        cp = __builtin_amdgcn_mfma_f32_16x16x32_f16(pack8(q00, q01), wp0, cp, 0, 0, 0);
        cb = __builtin_amdgcn_mfma_f32_16x16x32_f16(pack8(b10, b11), wa1, cb, 0, 0, 0);
        cp = __builtin_amdgcn_mfma_f32_16x16x32_f16(pack8(q10, q11), wp1, cp, 0, 0, 0);
        cb = __builtin_amdgcn_mfma_f32_16x16x32_f16(pack8(b20, b21), wa2, cb, 0, 0, 0);
        cp = __builtin_amdgcn_mfma_f32_16x16x32_f16(pack8(q20, q21), wp2, cp, 0, 0, 0);
        cb = __builtin_amdgcn_mfma_f32_16x16x32_f16(pack8(b30, b31), wa3, cb, 0, 0, 0);
        cp = __builtin_amdgcn_mfma_f32_16x16x32_f16(pack8(q30, q31), wp3, cp, 0, 0, 0);

        if (col < 8) {
            #pragma unroll
            for (int r = 0; r < 4; ++r) {
                const int row = qd * 4 + r;
                float v = cb[r];
                *(h2*)(lb + row * 80 + col * 4) =
                    pk2(fminf(v * v * (255.0f / 256.0f), 1.0f),
                        fminf(fmaxf(v, 0.0f), 1.0f));
                v = cp[r];
                *(h2*)(lb + row * 80 + 32 + col * 4) =
                    pk2(fminf(v * v * (255.0f / 256.0f), 1.0f),
                        fminf(fmaxf(v, 0.0f), 1.0f));
            }
        } else if (col == 8) {
            #pragma unroll
            for (int r = 0; r < 4; ++r) {
                const int row = qd * 4 + r;
                *(float*)(lb + row * 80 + 64) = cb[r];
                *(float*)(lb + row * 80 + 68) = cp[r];
            }
        }

        const h8 a2 = *(const h8*)(lb + col * 80 + qd * 16);
        const float s0 = sB2[bkt][col];
        const float s1 = sB2[bkt][16 + col];
        const float s2 = sB2[bkt][32 + col];
        const float s3 = sB2[bkt][48 + col];
        f4 c20 = {s0, s0, s0, s0};
        f4 c21 = {s1, s1, s1, s1};
        f4 c22 = {s2, s2, s2, s2};
        f4 c23 = {s3, s3, s3, s3};
        c20 = __builtin_amdgcn_mfma_f32_16x16x32_f16(a2, *(const h8*)&sW2[bkt][0][qd][col][0], c20, 0, 0, 0);
        c21 = __builtin_amdgcn_mfma_f32_16x16x32_f16(a2, *(const h8*)&sW2[bkt][1][qd][col][0], c21, 0, 0, 0);
        c22 = __builtin_amdgcn_mfma_f32_16x16x32_f16(a2, *(const h8*)&sW2[bkt][2][qd][col][0], c22, 0, 0, 0);
        c23 = __builtin_amdgcn_mfma_f32_16x16x32_f16(a2, *(const h8*)&sW2[bkt][3][qd][col][0], c23, 0, 0, 0);

        const float wo0 = sWo0[bkt][col];
        const float wo1 = sWo0[bkt][16 + col];
        const float wo2 = sWo0[bkt][32 + col];
        const float wo3 = sWo0[bkt][48 + col];
        float p0 = actv(c20[0]) * wo0 + actv(c21[0]) * wo1 + actv(c22[0]) * wo2 + actv(c23[0]) * wo3;
        float p1 = actv(c20[1]) * wo0 + actv(c21[1]) * wo1 + actv(c22[1]) * wo2 + actv(c23[1]) * wo3;
        float p2 = actv(c20[2]) * wo0 + actv(c21[2]) * wo1 + actv(c22[2]) * wo2 + actv(c23[2]) * wo3;
        float p3 = actv(c20[3]) * wo0 + actv(c21[3]) * wo1 + actv(c22[3]) * wo2 + actv(c23[3]) * wo3;
        #pragma unroll
        for (int m = 1; m < 16; m <<= 1) {
            p0 += __shfl_xor(p0, m, 64);
            p1 += __shfl_xor(p1, m, 64);
            p2 += __shfl_xor(p2, m, 64);
            p3 += __shfl_xor(p3, m, 64);
        }

        if (col == 0) {
            const float bo = sBout[bkt];
            if (sl0 >= 0)
                out[gbase + sl0] = bo + *(const float*)(lb + (qd * 4 + 0) * 80 + 64)
                                      + *(const float*)(lb + (qd * 4 + 0) * 80 + 68) + p0;
            if (sl1 >= 0)
                out[gbase + sl1] = bo + *(const float*)(lb + (qd * 4 + 1) * 80 + 64)
                                      + *(const float*)(lb + (qd * 4 + 1) * 80 + 68) + p1;
            if (sl2 >= 0)
                out[gbase + sl2] = bo + *(const float*)(lb + (qd * 4 + 2) * 80 + 64)
                                      + *(const float*)(lb + (qd * 4 + 2) * 80 + 68) + p2;
            if (sl3 >= 0)
                out[gbase + sl3] = bo + *(const float*)(lb + (qd * 4 + 3) * 80 + 64)
                                      + *(const float*)(lb + (qd * 4 + 3) * 80 + 68) + p3;
        }
    }
}

extern "C" void kernel_launch(void* const* d_in, const int* in_sizes, int n_in,
                              void* d_out, int out_size, void* d_ws, size_t ws_size,
                              hipStream_t stream) {
    const float* x_base   = (const float*)d_in[0];
    const float* x_pa     = (const float*)d_in[1];
    const float* mobility = (const float*)d_in[2];
    const int*   ply      = (const int*)d_in[3];
    const float* W1b      = (const float*)d_in[4];
    const float* b1b      = (const float*)d_in[5];
    const float* W1pa     = (const float*)d_in[6];
    const float* b1pa     = (const float*)d_in[7];
    const float* W2       = (const float*)d_in[8];
    const float* b2       = (const float*)d_in[9];
    const float* Wout     = (const float*)d_in[10];
    const float* bout     = (const float*)d_in[11];
    float* out = (float*)d_out;

    const int B = in_sizes[3];              // 262144 (multiple of 512)
    const int blocks = B / BT;              // 512
    layerstacks_mfma<<<blocks, BT, 0, stream>>>(
        x_base, x_pa, mobility, ply, W1b, b1b, W1pa, b1pa, W2, b2, Wout, bout, out);
}

// Round 16
// 62.333 us; speedup vs baseline: 1.5261x; 1.1259x over previous
//
#include <hip/hip_runtime.h>

// LayerStacks round 16: R15 fixed. The 16 x-loads AND the s_waitcnt vmcnt(0)
// live in ONE asm volatile block (tied "+v" float4 operands don't compile on
// gfx950 — "tied indirect register inputs"). Block outputs are data-valid on
// exit => consumers data-depend on the block => no hoist hazard, no tie
// needed. Effect unchanged: 16 loads issue back-to-back, ONE latency window
// per tile (R8-R14 evidence: compiler otherwise splits into ~8 windows with
// VGPR pinned at 64). Everything else identical to R10 (best, 60.8us).

#define NB 6
#define BT 512
#define NW (BT / 64)

typedef _Float16 h2 __attribute__((ext_vector_type(2)));
typedef _Float16 h8 __attribute__((ext_vector_type(8)));
typedef float f4 __attribute__((ext_vector_type(4)));

__device__ __forceinline__ h2 pk2(float x, float y) {
    return __builtin_bit_cast(h2, __builtin_amdgcn_cvt_pkrtz(x, y));
}

__device__ __forceinline__ h8 pack8(const float4 a, const float4 b) {
    h2 p0 = pk2(a.x, a.y), p1 = pk2(a.z, a.w);
    h2 p2 = pk2(b.x, b.y), p3 = pk2(b.z, b.w);
    h8 r;
    r[0] = p0[0]; r[1] = p0[1]; r[2] = p1[0]; r[3] = p1[1];
    r[4] = p2[0]; r[5] = p2[1]; r[6] = p3[0]; r[7] = p3[1];
    return r;
}

__device__ __forceinline__ float actv(float v) {
    float u = fminf(fmaxf(v, 0.0f), 1.0f);
    return u * u * (255.0f / 256.0f);
}

__global__ __launch_bounds__(BT, 4)
void layerstacks_mfma(const float* __restrict__ x_base,
                      const float* __restrict__ x_pa,
                      const float* __restrict__ mobility,
                      const int*   __restrict__ ply,
                      const float* __restrict__ W1b,
                      const float* __restrict__ b1b,
                      const float* __restrict__ W1pa,
                      const float* __restrict__ b1pa,
                      const float* __restrict__ W2,
                      const float* __restrict__ b2,
                      const float* __restrict__ Wout,
                      const float* __restrict__ bout,
                      float* __restrict__ out)
{
    __shared__ __align__(16) _Float16 sW1[NB][2][4][4][9][8];   // 27.6 KB
    __shared__ __align__(16) _Float16 sW2[NB][4][4][16][8];     // 24.6 KB
    __shared__ float sWo0[NB][64];
    __shared__ float sB2[NB][64];
    __shared__ float sB1[NB][4][8];
    __shared__ float sBout[NB];
    __shared__ float sMob[BT];
    __shared__ int   sList[BT + NB * 16];
    __shared__ __align__(16) char sL1[NW * 1280];
    __shared__ int sCnt[8], sCur[8], sTb[40];
    __shared__ int sNt;

    const int tid   = threadIdx.x;
    const int lane  = tid & 63;
    const int w     = tid >> 6;
    const int gbase = blockIdx.x * BT;

    // ---------------- phase 0: staging --------------------------------------
    if (tid < 8) { sCnt[tid] = 0; }

    for (int e = tid; e < NB * 2 * 4 * 4 * 9 * 8; e += BT) {
        int i = e & 7;
        int rest = e >> 3;
        int n = rest % 9;   rest /= 9;
        int kb = rest & 3;  rest >>= 2;
        int t = rest & 3;   rest >>= 2;
        int st = rest & 1;
        int b = rest >> 1;
        int k = t * 32 + kb * 8 + i;
        float v;
        if (n < 8) {
            const float* Wx = st ? W1pa : W1b;
            v = Wx[b * 1032 + n * 129 + k];
        } else {
            v = st ? Wout[b * 320 + 192 + k] : Wout[b * 320 + 64 + k];
        }
        sW1[b][st][t][kb][n][i] = (_Float16)v;
    }
    for (int e = tid; e < NB * 4 * 4 * 16 * 8; e += BT) {
        int i = e & 7;
        int j = (e >> 3) & 15;
        int kb = (e >> 7) & 3;
        int T = (e >> 9) & 3;
        int b = e >> 11;
        int n = T * 16 + j;
        int k = kb * 8 + i;
        int u = k >> 1;
        int colw = (k & 1) ? (16 + u) : u;
        sW2[b][T][kb][j][i] = (_Float16)W2[b * 2048 + n * 32 + colw];
    }
    for (int e = tid; e < NB * 64; e += BT) {
        int b = e >> 6, n = e & 63;
        sWo0[b][n] = Wout[b * 320 + n];
        sB2[b][n]  = b2[e];
    }
    if (tid < NB * 4 * 8) {
        int n = tid & 7, which = (tid >> 3) & 3, b = tid >> 5;
        float v;
        if (which == 0)      v = b1b[b * 8 + n];
        else if (which == 1) v = b1pa[b * 8 + n];
        else if (which == 2) v = W1b [b * 1032 + n * 129 + 128];
        else                 v = W1pa[b * 1032 + n * 129 + 128];
        sB1[b][which][n] = v;
    }
    if (tid < NB) sBout[tid] = bout[tid];
    sMob[tid] = fminf(mobility[gbase + tid] * (7.0f / 255.0f), 1.0f);
    for (int e = tid; e < BT + NB * 16; e += BT) sList[e] = -1;

    const int bb = ply[gbase + tid] / 10;
    __syncthreads();

    // ---------------- phase 1: ballot-aggregated counts ---------------------
    #pragma unroll
    for (int b = 0; b < NB; ++b) {
        unsigned long long mk = __ballot(bb == b);
        if (bb == b) {
            int lead = __ffsll((long long)mk) - 1;
            if (lane == lead) atomicAdd(&sCnt[b], __popcll(mk));
        }
    }
    __syncthreads();

    // ---------------- phase 2: offsets + tile->bucket map -------------------
    if (tid == 0) {
        int off = 0, tt = 0;
        for (int b = 0; b < NB; ++b) {
            sCur[b] = off;
            int ntl = (sCnt[b] + 15) >> 4;
            for (int q = 0; q < ntl; ++q) sTb[tt++] = b;
            off += ntl << 4;
        }
        sNt = tt;
    }
    __syncthreads();

    // ---------------- phase 3: scatter local indices ------------------------
    #pragma unroll
    for (int b = 0; b < NB; ++b) {
        unsigned long long mk = __ballot(bb == b);
        if (bb == b) {
            int lead = __ffsll((long long)mk) - 1;
            int pfx = __popcll(mk & ((1ull << lane) - 1ull));
            int base = 0;
            if (lane == lead) base = atomicAdd(&sCur[b], __popcll(mk));
            base = __shfl(base, lead);
            sList[base + pfx] = tid;
        }
    }
    __syncthreads();

    // ---------------- main: per-wave MFMA tiles -----------------------------
    const int ntiles = sNt;
    const int col = lane & 15;
    const int qd  = lane >> 4;
    char* lb = sL1 + w * 1280;

    for (int tl = w; tl < ntiles; tl += NW) {
        const int bkt = sTb[tl];
        const int t16 = tl << 4;

        const int sl0 = sList[t16 + qd * 4 + 0];
        const int sl1 = sList[t16 + qd * 4 + 1];
        const int sl2 = sList[t16 + qd * 4 + 2];
        const int sl3 = sList[t16 + qd * 4 + 3];
        int sA = sList[t16 + col];
        if (sA < 0) sA = sList[t16];

        const float* xbrow = x_base + (size_t)(gbase + sA) * 128 + qd * 8;
        const float* xprow = x_pa   + (size_t)(gbase + sA) * 128 + qd * 8;

        // ==== 16 loads + single waitcnt, one opaque asm block ===============
        float4 b00, b01, b10, b11, b20, b21, b30, b31;
        float4 q00, q01, q10, q11, q20, q21, q30, q31;
        asm volatile(
            "global_load_dwordx4 %0,  %[ab], off\n\t"
            "global_load_dwordx4 %1,  %[ab], off offset:16\n\t"
            "global_load_dwordx4 %2,  %[ab], off offset:128\n\t"
            "global_load_dwordx4 %3,  %[ab], off offset:144\n\t"
            "global_load_dwordx4 %4,  %[ab], off offset:256\n\t"
            "global_load_dwordx4 %5,  %[ab], off offset:272\n\t"
            "global_load_dwordx4 %6,  %[ab], off offset:384\n\t"
            "global_load_dwordx4 %7,  %[ab], off offset:400\n\t"
            "global_load_dwordx4 %8,  %[ap], off\n\t"
            "global_load_dwordx4 %9,  %[ap], off offset:16\n\t"
            "global_load_dwordx4 %10, %[ap], off offset:128\n\t"
            "global_load_dwordx4 %11, %[ap], off offset:144\n\t"
            "global_load_dwordx4 %12, %[ap], off offset:256\n\t"
            "global_load_dwordx4 %13, %[ap], off offset:272\n\t"
            "global_load_dwordx4 %14, %[ap], off offset:384\n\t"
            "global_load_dwordx4 %15, %[ap], off offset:400\n\t"
            "s_waitcnt vmcnt(0)"
            : "=v"(b00), "=v"(b01), "=v"(b10), "=v"(b11),
              "=v"(b20), "=v"(b21), "=v"(b30), "=v"(b31),
              "=v"(q00), "=v"(q01), "=v"(q10), "=v"(q11),
              "=v"(q20), "=v"(q21), "=v"(q30), "=v"(q31)
            : [ab] "v"(xbrow), [ap] "v"(xprow)
            : "memory");

        // ==== seeds / weights / MFMA chains =================================
        const float mob0 = (sl0 >= 0) ? sMob[sl0] : 0.0f;
        const float mob1 = (sl1 >= 0) ? sMob[sl1] : 0.0f;
        const float mob2 = (sl2 >= 0) ? sMob[sl2] : 0.0f;
        const float mob3 = (sl3 >= 0) ? sMob[sl3] : 0.0f;

        const int c7 = col & 7;
        const bool a8 = (col < 8);
        const int ncl = a8 ? col : 8;
        const float bb1 = sB1[bkt][0][c7], bp1 = sB1[bkt][1][c7];
        const float mwb = sB1[bkt][2][c7], mwp = sB1[bkt][3][c7];

        f4 cb, cp;
        cb[0] = a8 ? bb1 + mwb * mob0 : 0.0f;
        cb[1] = a8 ? bb1 + mwb * mob1 : 0.0f;
        cb[2] = a8 ? bb1 + mwb * mob2 : 0.0f;
        cb[3] = a8 ? bb1 + mwb * mob3 : 0.0f;
        cp[0] = a8 ? bp1 + mwp * mob0 : 0.0f;
        cp[1] = a8 ? bp1 + mwp * mob1 : 0.0f;
        cp[2] = a8 ? bp1 + mwp * mob2 : 0.0f;
        cp[3] = a8 ? bp1 + mwp * mob3 : 0.0f;

        const h8 wa0 = *(const h8*)&sW1[bkt][0][0][qd][ncl][0];
        const h8 wa1 = *(const h8*)&sW1[bkt][0][1][qd][ncl][0];
        const h8 wa2 = *(const h8*)&sW1[bkt][0][2][qd][ncl][0];
        const h8 wa3 = *(const h8*)&sW1[bkt][0][3][qd][ncl][0];
        const h8 wp0 = *(const h8*)&sW1[bkt][1][0][qd][ncl][0];
        const h8 wp1 = *(const h8*)&sW1[bkt][1][1][qd][ncl][0];
        const h8 wp2 = *(const h8*)&sW1[bkt][1][2][qd][ncl][0];
        const h8 wp3 = *(const h8*)&sW1[bkt][1][3][qd][ncl][0];

        cb = __builtin_amdgcn_mfma_f32_16x16x32_f16(pack8(b00, b01), wa0, cb, 0, 0, 0);
        cp = __builtin_amdgcn_mfma_f32_16x16x32_f16(pack8(q00, q01), wp0, cp, 0, 0, 0);
        cb = __builtin_amdgcn_mfma_f32_16x16x32_f16(pack8(b10, b11), wa1, cb, 0, 0, 0);
        cp = __builtin_amdgcn_mfma_f32_16x16x32_f16(pack8(q10, q11), wp1, cp, 0, 0, 0);
        cb = __builtin_amdgcn_mfma_f32_16x16x32_f16(pack8(b20, b21), wa2, cb, 0, 0, 0);
        cp = __builtin_amdgcn_mfma_f32_16x16x32_f16(pack8(q20, q21), wp2, cp, 0, 0, 0);
        cb = __builtin_amdgcn_mfma_f32_16x16x32_f16(pack8(b30, b31), wa3, cb, 0, 0, 0);
        cp = __builtin_amdgcn_mfma_f32_16x16x32_f16(pack8(q30, q31), wp3, cp, 0, 0, 0);

        if (col < 8) {
            #pragma unroll
            for (int r = 0; r < 4; ++r) {
                const int row = qd * 4 + r;
                float v = cb[r];
                *(h2*)(lb + row * 80 + col * 4) =
                    pk2(fminf(v * v * (255.0f / 256.0f), 1.0f),
                        fminf(fmaxf(v, 0.0f), 1.0f));
                v = cp[r];
                *(h2*)(lb + row * 80 + 32 + col * 4) =
                    pk2(fminf(v * v * (255.0f / 256.0f), 1.0f),
                        fminf(fmaxf(v, 0.0f), 1.0f));
            }
        } else if (col == 8) {
            #pragma unroll
            for (int r = 0; r < 4; ++r) {
                const int row = qd * 4 + r;
                *(float*)(lb + row * 80 + 64) = cb[r];
                *(float*)(lb + row * 80 + 68) = cp[r];
            }
        }

        const h8 a2 = *(const h8*)(lb + col * 80 + qd * 16);
        const float s0 = sB2[bkt][col];
        const float s1 = sB2[bkt][16 + col];
        const float s2 = sB2[bkt][32 + col];
        const float s3 = sB2[bkt][48 + col];
        f4 c20 = {s0, s0, s0, s0};
        f4 c21 = {s1, s1, s1, s1};
        f4 c22 = {s2, s2, s2, s2};
        f4 c23 = {s3, s3, s3, s3};
        c20 = __builtin_amdgcn_mfma_f32_16x16x32_f16(a2, *(const h8*)&sW2[bkt][0][qd][col][0], c20, 0, 0, 0);
        c21 = __builtin_amdgcn_mfma_f32_16x16x32_f16(a2, *(const h8*)&sW2[bkt][1][qd][col][0], c21, 0, 0, 0);
        c22 = __builtin_amdgcn_mfma_f32_16x16x32_f16(a2, *(const h8*)&sW2[bkt][2][qd][col][0], c22, 0, 0, 0);
        c23 = __builtin_amdgcn_mfma_f32_16x16x32_f16(a2, *(const h8*)&sW2[bkt][3][qd][col][0], c23, 0, 0, 0);

        const float wo0 = sWo0[bkt][col];
        const float wo1 = sWo0[bkt][16 + col];
        const float wo2 = sWo0[bkt][32 + col];
        const float wo3 = sWo0[bkt][48 + col];
        float p0 = actv(c20[0]) * wo0 + actv(c21[0]) * wo1 + actv(c22[0]) * wo2 + actv(c23[0]) * wo3;
        float p1 = actv(c20[1]) * wo0 + actv(c21[1]) * wo1 + actv(c22[1]) * wo2 + actv(c23[1]) * wo3;
        float p2 = actv(c20[2]) * wo0 + actv(c21[2]) * wo1 + actv(c22[2]) * wo2 + actv(c23[2]) * wo3;
        float p3 = actv(c20[3]) * wo0 + actv(c21[3]) * wo1 + actv(c22[3]) * wo2 + actv(c23[3]) * wo3;
        #pragma unroll
        for (int m = 1; m < 16; m <<= 1) {
            p0 += __shfl_xor(p0, m, 64);
            p1 += __shfl_xor(p1, m, 64);
            p2 += __shfl_xor(p2, m, 64);
            p3 += __shfl_xor(p3, m, 64);
        }

        if (col == 0) {
            const float bo = sBout[bkt];
            if (sl0 >= 0)
                out[gbase + sl0] = bo + *(const float*)(lb + (qd * 4 + 0) * 80 + 64)
                                      + *(const float*)(lb + (qd * 4 + 0) * 80 + 68) + p0;
            if (sl1 >= 0)
                out[gbase + sl1] = bo + *(const float*)(lb + (qd * 4 + 1) * 80 + 64)
                                      + *(const float*)(lb + (qd * 4 + 1) * 80 + 68) + p1;
            if (sl2 >= 0)
                out[gbase + sl2] = bo + *(const float*)(lb + (qd * 4 + 2) * 80 + 64)
                                      + *(const float*)(lb + (qd * 4 + 2) * 80 + 68) + p2;
            if (sl3 >= 0)
                out[gbase + sl3] = bo + *(const float*)(lb + (qd * 4 + 3) * 80 + 64)
                                      + *(const float*)(lb + (qd * 4 + 3) * 80 + 68) + p3;
        }
    }
}

extern "C" void kernel_launch(void* const* d_in, const int* in_sizes, int n_in,
                              void* d_out, int out_size, void* d_ws, size_t ws_size,
                              hipStream_t stream) {
    const float* x_base   = (const float*)d_in[0];
    const float* x_pa     = (const float*)d_in[1];
    const float* mobility = (const float*)d_in[2];
    const int*   ply      = (const int*)d_in[3];
    const float* W1b      = (const float*)d_in[4];
    const float* b1b      = (const float*)d_in[5];
    const float* W1pa     = (const float*)d_in[6];
    const float* b1pa     = (const float*)d_in[7];
    const float* W2       = (const float*)d_in[8];
    const float* b2       = (const float*)d_in[9];
    const float* Wout     = (const float*)d_in[10];
    const float* bout     = (const float*)d_in[11];
    float* out = (float*)d_out;

    const int B = in_sizes[3];              // 262144 (multiple of 512)
    const int blocks = B / BT;              // 512
    layerstacks_mfma<<<blocks, BT, 0, stream>>>(
        x_base, x_pa, mobility, ply, W1b, b1b, W1pa, b1pa, W2, b2, Wout, bout, out);
}

// Round 17
// 57.728 us; speedup vs baseline: 1.6478x; 1.0798x over previous
//
#include <hip/hip_runtime.h>

// LayerStacks round 17: NATURAL-ORDER tiles + bucket masking.
// R8-R16 evidence: grouped (permuted) tiles scatter the x gather over 512KB
// per block -> L2 thrash -> L3/HBM tail latency that no scheduling/occupancy
// lever fixed (R12/R13/R16 all null). This round removes the permutation:
// tile t = samples 16t..16t+15 (one contiguous 16KB region), and bucket
// mixing is handled inside the MFMA: C = sum_b (mask_b . A) x W_b, masking
// the A fragment per lane (sample) and accumulating all 6 buckets into the
// same C. MFMA x6 (MfmaUtil was 1% - free); absent buckets skipped via __any.
// The whole sort machinery (3 phases, sList, padding) is deleted.

#define NB 6
#define BT 512
#define NW (BT / 64)
#define TILES (BT / 16)     // 32 tiles per block

typedef _Float16 h2 __attribute__((ext_vector_type(2)));
typedef _Float16 h8 __attribute__((ext_vector_type(8)));
typedef float f4 __attribute__((ext_vector_type(4)));
typedef unsigned u4v __attribute__((ext_vector_type(4)));

__device__ __forceinline__ h2 pk2(float x, float y) {
    return __builtin_bit_cast(h2, __builtin_amdgcn_cvt_pkrtz(x, y));
}

__device__ __forceinline__ h8 pack8(const float4 a, const float4 b) {
    h2 p0 = pk2(a.x, a.y), p1 = pk2(a.z, a.w);
    h2 p2 = pk2(b.x, b.y), p3 = pk2(b.z, b.w);
    h8 r;
    r[0] = p0[0]; r[1] = p0[1]; r[2] = p1[0]; r[3] = p1[1];
    r[4] = p2[0]; r[5] = p2[1]; r[6] = p3[0]; r[7] = p3[1];
    return r;
}

__device__ __forceinline__ h8 mask8(h8 v, unsigned m) {
    u4v u = __builtin_bit_cast(u4v, v);
    u4v mm = {m, m, m, m};
    u &= mm;
    return __builtin_bit_cast(h8, u);
}

__device__ __forceinline__ float actv(float v) {
    float u = fminf(fmaxf(v, 0.0f), 1.0f);
    return u * u * (255.0f / 256.0f);
}

__global__ __launch_bounds__(BT, 4)
void layerstacks_mfma(const float* __restrict__ x_base,
                      const float* __restrict__ x_pa,
                      const float* __restrict__ mobility,
                      const int*   __restrict__ ply,
                      const float* __restrict__ W1b,
                      const float* __restrict__ b1b,
                      const float* __restrict__ W1pa,
                      const float* __restrict__ b1pa,
                      const float* __restrict__ W2,
                      const float* __restrict__ b2,
                      const float* __restrict__ Wout,
                      const float* __restrict__ bout,
                      float* __restrict__ out)
{
    __shared__ __align__(16) _Float16 sW1[NB][2][4][4][9][8];   // 27.6 KB
    __shared__ __align__(16) _Float16 sW2[NB][4][4][16][8];     // 24.6 KB
    __shared__ float sWo0[NB][64];
    __shared__ float sB2[NB][64];
    __shared__ float sB1[NB][4][8];
    __shared__ float sBout[NB];
    __shared__ float sMob[BT];
    __shared__ int   sBkt[BT];
    __shared__ __align__(16) char sL1[NW * 1280];

    const int tid   = threadIdx.x;
    const int lane  = tid & 63;
    const int w     = tid >> 6;
    const int gbase = blockIdx.x * BT;

    // ---------------- phase 0: staging --------------------------------------
    for (int e = tid; e < NB * 2 * 4 * 4 * 9 * 8; e += BT) {
        int i = e & 7;
        int rest = e >> 3;
        int n = rest % 9;   rest /= 9;
        int kb = rest & 3;  rest >>= 2;
        int t = rest & 3;   rest >>= 2;
        int st = rest & 1;
        int b = rest >> 1;
        int k = t * 32 + kb * 8 + i;
        float v;
        if (n < 8) {
            const float* Wx = st ? W1pa : W1b;
            v = Wx[b * 1032 + n * 129 + k];
        } else {
            v = st ? Wout[b * 320 + 192 + k] : Wout[b * 320 + 64 + k];
        }
        sW1[b][st][t][kb][n][i] = (_Float16)v;
    }
    for (int e = tid; e < NB * 4 * 4 * 16 * 8; e += BT) {
        int i = e & 7;
        int j = (e >> 3) & 15;
        int kb = (e >> 7) & 3;
        int T = (e >> 9) & 3;
        int b = e >> 11;
        int n = T * 16 + j;
        int k = kb * 8 + i;
        int u = k >> 1;
        int colw = (k & 1) ? (16 + u) : u;
        sW2[b][T][kb][j][i] = (_Float16)W2[b * 2048 + n * 32 + colw];
    }
    for (int e = tid; e < NB * 64; e += BT) {
        int b = e >> 6, n = e & 63;
        sWo0[b][n] = Wout[b * 320 + n];
        sB2[b][n]  = b2[e];
    }
    if (tid < NB * 4 * 8) {
        int n = tid & 7, which = (tid >> 3) & 3, b = tid >> 5;
        float v;
        if (which == 0)      v = b1b[b * 8 + n];
        else if (which == 1) v = b1pa[b * 8 + n];
        else if (which == 2) v = W1b [b * 1032 + n * 129 + 128];
        else                 v = W1pa[b * 1032 + n * 129 + 128];
        sB1[b][which][n] = v;
    }
    if (tid < NB) sBout[tid] = bout[tid];
    sMob[tid] = fminf(mobility[gbase + tid] * (7.0f / 255.0f), 1.0f);
    sBkt[tid] = ply[gbase + tid] / 10;
    __syncthreads();

    // ---------------- main: natural-order tiles, bucket-masked MFMA ---------
    const int col = lane & 15;
    const int qd  = lane >> 4;
    char* lb = sL1 + w * 1280;

    for (int tl = w; tl < TILES; tl += NW) {
        const int t16 = tl << 4;
        const int r0 = t16 + qd * 4;

        // ---- 16 x loads (CONSECUTIVE rows) + single waitcnt, opaque asm ----
        const float* xbrow = x_base + (size_t)(gbase + t16 + col) * 128 + qd * 8;
        const float* xprow = x_pa   + (size_t)(gbase + t16 + col) * 128 + qd * 8;
        float4 b00, b01, b10, b11, b20, b21, b30, b31;
        float4 q00, q01, q10, q11, q20, q21, q30, q31;
        asm volatile(
            "global_load_dwordx4 %0,  %[ab], off\n\t"
            "global_load_dwordx4 %1,  %[ab], off offset:16\n\t"
            "global_load_dwordx4 %2,  %[ab], off offset:128\n\t"
            "global_load_dwordx4 %3,  %[ab], off offset:144\n\t"
            "global_load_dwordx4 %4,  %[ab], off offset:256\n\t"
            "global_load_dwordx4 %5,  %[ab], off offset:272\n\t"
            "global_load_dwordx4 %6,  %[ab], off offset:384\n\t"
            "global_load_dwordx4 %7,  %[ab], off offset:400\n\t"
            "global_load_dwordx4 %8,  %[ap], off\n\t"
            "global_load_dwordx4 %9,  %[ap], off offset:16\n\t"
            "global_load_dwordx4 %10, %[ap], off offset:128\n\t"
            "global_load_dwordx4 %11, %[ap], off offset:144\n\t"
            "global_load_dwordx4 %12, %[ap], off offset:256\n\t"
            "global_load_dwordx4 %13, %[ap], off offset:272\n\t"
            "global_load_dwordx4 %14, %[ap], off offset:384\n\t"
            "global_load_dwordx4 %15, %[ap], off offset:400\n\t"
            "s_waitcnt vmcnt(0)"
            : "=v"(b00), "=v"(b01), "=v"(b10), "=v"(b11),
              "=v"(b20), "=v"(b21), "=v"(b30), "=v"(b31),
              "=v"(q00), "=v"(q01), "=v"(q10), "=v"(q11),
              "=v"(q20), "=v"(q21), "=v"(q30), "=v"(q31)
            : [ab] "v"(xbrow), [ap] "v"(xprow)
            : "memory");

        // pack once
        const h8 xa0 = pack8(b00, b01), xa1 = pack8(b10, b11);
        const h8 xa2 = pack8(b20, b21), xa3 = pack8(b30, b31);
        const h8 xp0 = pack8(q00, q01), xp1 = pack8(q10, q11);
        const h8 xp2 = pack8(q20, q21), xp3 = pack8(q30, q31);

        // per-lane (A-row = sample col) bucket; per-C-row buckets
        const int bbA = sBkt[t16 + col];
        const int bk0 = sBkt[r0 + 0], bk1 = sBkt[r0 + 1];
        const int bk2 = sBkt[r0 + 2], bk3 = sBkt[r0 + 3];
        const float m0 = sMob[r0 + 0], m1 = sMob[r0 + 1];
        const float m2 = sMob[r0 + 2], m3 = sMob[r0 + 3];

        const int c7 = col & 7;
        const bool a8 = (col < 8);
        const int ncl = a8 ? col : 8;

        // ---- stage 1 seeds (per-row bucket) --------------------------------
        f4 cb, cp;
        cb[0] = a8 ? sB1[bk0][0][c7] + sB1[bk0][2][c7] * m0 : 0.0f;
        cb[1] = a8 ? sB1[bk1][0][c7] + sB1[bk1][2][c7] * m1 : 0.0f;
        cb[2] = a8 ? sB1[bk2][0][c7] + sB1[bk2][2][c7] * m2 : 0.0f;
        cb[3] = a8 ? sB1[bk3][0][c7] + sB1[bk3][2][c7] * m3 : 0.0f;
        cp[0] = a8 ? sB1[bk0][1][c7] + sB1[bk0][3][c7] * m0 : 0.0f;
        cp[1] = a8 ? sB1[bk1][1][c7] + sB1[bk1][3][c7] * m1 : 0.0f;
        cp[2] = a8 ? sB1[bk2][1][c7] + sB1[bk2][3][c7] * m2 : 0.0f;
        cp[3] = a8 ? sB1[bk3][1][c7] + sB1[bk3][3][c7] * m3 : 0.0f;

        // ---- stage 1: accumulate over buckets with masked A ----------------
        #pragma unroll
        for (int b = 0; b < NB; ++b) {
            if (!__any(bbA == b)) continue;
            const unsigned mA = (bbA == b) ? 0xFFFFFFFFu : 0u;
            cb = __builtin_amdgcn_mfma_f32_16x16x32_f16(mask8(xa0, mA), *(const h8*)&sW1[b][0][0][qd][ncl][0], cb, 0, 0, 0);
            cp = __builtin_amdgcn_mfma_f32_16x16x32_f16(mask8(xp0, mA), *(const h8*)&sW1[b][1][0][qd][ncl][0], cp, 0, 0, 0);
            cb = __builtin_amdgcn_mfma_f32_16x16x32_f16(mask8(xa1, mA), *(const h8*)&sW1[b][0][1][qd][ncl][0], cb, 0, 0, 0);
            cp = __builtin_amdgcn_mfma_f32_16x16x32_f16(mask8(xp1, mA), *(const h8*)&sW1[b][1][1][qd][ncl][0], cp, 0, 0, 0);
            cb = __builtin_amdgcn_mfma_f32_16x16x32_f16(mask8(xa2, mA), *(const h8*)&sW1[b][0][2][qd][ncl][0], cb, 0, 0, 0);
            cp = __builtin_amdgcn_mfma_f32_16x16x32_f16(mask8(xp2, mA), *(const h8*)&sW1[b][1][2][qd][ncl][0], cp, 0, 0, 0);
            cb = __builtin_amdgcn_mfma_f32_16x16x32_f16(mask8(xa3, mA), *(const h8*)&sW1[b][0][3][qd][ncl][0], cb, 0, 0, 0);
            cp = __builtin_amdgcn_mfma_f32_16x16x32_f16(mask8(xp3, mA), *(const h8*)&sW1[b][1][3][qd][ncl][0], cp, 0, 0, 0);
        }

        // ---- epilogue 1: l1c pairs -> per-wave scratch ---------------------
        if (col < 8) {
            #pragma unroll
            for (int r = 0; r < 4; ++r) {
                const int row = qd * 4 + r;
                float v = cb[r];
                *(h2*)(lb + row * 80 + col * 4) =
                    pk2(fminf(v * v * (255.0f / 256.0f), 1.0f),
                        fminf(fmaxf(v, 0.0f), 1.0f));
                v = cp[r];
                *(h2*)(lb + row * 80 + 32 + col * 4) =
                    pk2(fminf(v * v * (255.0f / 256.0f), 1.0f),
                        fminf(fmaxf(v, 0.0f), 1.0f));
            }
        } else if (col == 8) {
            #pragma unroll
            for (int r = 0; r < 4; ++r) {
                const int row = qd * 4 + r;
                *(float*)(lb + row * 80 + 64) = cb[r];
                *(float*)(lb + row * 80 + 68) = cp[r];
            }
        }

        // ---- stage 2: L2 (K=32), bucket-masked A ---------------------------
        const h8 a2 = *(const h8*)(lb + col * 80 + qd * 16);
        f4 c20, c21, c22, c23;
        c20[0] = sB2[bk0][col];      c20[1] = sB2[bk1][col];
        c20[2] = sB2[bk2][col];      c20[3] = sB2[bk3][col];
        c21[0] = sB2[bk0][16 + col]; c21[1] = sB2[bk1][16 + col];
        c21[2] = sB2[bk2][16 + col]; c21[3] = sB2[bk3][16 + col];
        c22[0] = sB2[bk0][32 + col]; c22[1] = sB2[bk1][32 + col];
        c22[2] = sB2[bk2][32 + col]; c22[3] = sB2[bk3][32 + col];
        c23[0] = sB2[bk0][48 + col]; c23[1] = sB2[bk1][48 + col];
        c23[2] = sB2[bk2][48 + col]; c23[3] = sB2[bk3][48 + col];

        #pragma unroll
        for (int b = 0; b < NB; ++b) {
            if (!__any(bbA == b)) continue;
            const unsigned mA = (bbA == b) ? 0xFFFFFFFFu : 0u;
            const h8 a2m = mask8(a2, mA);
            c20 = __builtin_amdgcn_mfma_f32_16x16x32_f16(a2m, *(const h8*)&sW2[b][0][qd][col][0], c20, 0, 0, 0);
            c21 = __builtin_amdgcn_mfma_f32_16x16x32_f16(a2m, *(const h8*)&sW2[b][1][qd][col][0], c21, 0, 0, 0);
            c22 = __builtin_amdgcn_mfma_f32_16x16x32_f16(a2m, *(const h8*)&sW2[b][2][qd][col][0], c22, 0, 0, 0);
            c23 = __builtin_amdgcn_mfma_f32_16x16x32_f16(a2m, *(const h8*)&sW2[b][3][qd][col][0], c23, 0, 0, 0);
        }

        // ---- epilogue 2: activation + per-row Wout[0:64) dot + reduce ------
        float p0 = actv(c20[0]) * sWo0[bk0][col]      + actv(c21[0]) * sWo0[bk0][16 + col]
                 + actv(c22[0]) * sWo0[bk0][32 + col] + actv(c23[0]) * sWo0[bk0][48 + col];
        float p1 = actv(c20[1]) * sWo0[bk1][col]      + actv(c21[1]) * sWo0[bk1][16 + col]
                 + actv(c22[1]) * sWo0[bk1][32 + col] + actv(c23[1]) * sWo0[bk1][48 + col];
        float p2 = actv(c20[2]) * sWo0[bk2][col]      + actv(c21[2]) * sWo0[bk2][16 + col]
                 + actv(c22[2]) * sWo0[bk2][32 + col] + actv(c23[2]) * sWo0[bk2][48 + col];
        float p3 = actv(c20[3]) * sWo0[bk3][col]      + actv(c21[3]) * sWo0[bk3][16 + col]
                 + actv(c22[3]) * sWo0[bk3][32 + col] + actv(c23[3]) * sWo0[bk3][48 + col];
        #pragma unroll
        for (int m = 1; m < 16; m <<= 1) {
            p0 += __shfl_xor(p0, m, 64);
            p1 += __shfl_xor(p1, m, 64);
            p2 += __shfl_xor(p2, m, 64);
            p3 += __shfl_xor(p3, m, 64);
        }

        if (col == 0) {
            out[gbase + r0 + 0] = sBout[bk0]
                + *(const float*)(lb + (qd * 4 + 0) * 80 + 64)
                + *(const float*)(lb + (qd * 4 + 0) * 80 + 68) + p0;
            out[gbase + r0 + 1] = sBout[bk1]
                + *(const float*)(lb + (qd * 4 + 1) * 80 + 64)
                + *(const float*)(lb + (qd * 4 + 1) * 80 + 68) + p1;
            out[gbase + r0 + 2] = sBout[bk2]
                + *(const float*)(lb + (qd * 4 + 2) * 80 + 64)
                + *(const float*)(lb + (qd * 4 + 2) * 80 + 68) + p2;
            out[gbase + r0 + 3] = sBout[bk3]
                + *(const float*)(lb + (qd * 4 + 3) * 80 + 64)
                + *(const float*)(lb + (qd * 4 + 3) * 80 + 68) + p3;
        }
    }
}

extern "C" void kernel_launch(void* const* d_in, const int* in_sizes, int n_in,
                              void* d_out, int out_size, void* d_ws, size_t ws_size,
                              hipStream_t stream) {
    const float* x_base   = (const float*)d_in[0];
    const float* x_pa     = (const float*)d_in[1];
    const float* mobility = (const float*)d_in[2];
    const int*   ply      = (const int*)d_in[3];
    const float* W1b      = (const float*)d_in[4];
    const float* b1b      = (const float*)d_in[5];
    const float* W1pa     = (const float*)d_in[6];
    const float* b1pa     = (const float*)d_in[7];
    const float* W2       = (const float*)d_in[8];
    const float* b2       = (const float*)d_in[9];
    const float* Wout     = (const float*)d_in[10];
    const float* bout     = (const float*)d_in[11];
    float* out = (float*)d_out;

    const int B = in_sizes[3];              // 262144 (multiple of 512)
    const int blocks = B / BT;              // 512
    layerstacks_mfma<<<blocks, BT, 0, stream>>>(
        x_base, x_pa, mobility, ply, W1b, b1b, W1pa, b1pa, W2, b2, Wout, bout, out);
}